// Round 9
// baseline (168.575 us; speedup 1.0000x reference)
//
#include <hip/hip_runtime.h>

typedef _Float16 half8 __attribute__((ext_vector_type(8)));
typedef _Float16 half2v __attribute__((ext_vector_type(2)));
typedef float f32x4 __attribute__((ext_vector_type(4)));
typedef unsigned int uint2v __attribute__((ext_vector_type(2)));
typedef unsigned int uint4v __attribute__((ext_vector_type(4)));

#define HID 50
#define KSC 2.8853900817779268f   // 2*log2(e), folded into all W/b at prep

// r = 1/(1 + 2^a)  where a = 2*log2(e)*s  =>  tanh(s) = 1 - 2r
__device__ __forceinline__ float sigr(float a) {
    return __builtin_amdgcn_rcpf(1.0f + __builtin_amdgcn_exp2f(a));
}
__device__ __forceinline__ half2v pk2h(float a, float b) {
    return __builtin_bit_cast(half2v, __builtin_amdgcn_cvt_pkrtz(a, b));
}
__device__ __forceinline__ unsigned int h2u(half2v h) {
    return __builtin_bit_cast(unsigned int, h);
}

// ---------- weight prep: 45 blocks x 64 threads ----------
// half8-block b, lane l (g=l>>4, cl=l&15), elem v -> W[k = 8g+v (+32ks)][col = cl+16nt]
//   b in [0,12):  UVH  b = m*4 + nt           (K=32 padded from 12, bias folded at k==1)
//   b in [12,44): Z    b = 12 + (li*4+nt)*2 + ks  (K=64 padded from 50, bias row at k==50)
//   block 44: F_W padded to 64 floats at f16-offset 22528
// All UVH/Z weights and biases pre-scaled by KSC (they only feed tanh).
__global__ void prep_weights(const float* __restrict__ U_W, const float* __restrict__ U_b,
                             const float* __restrict__ V_W, const float* __restrict__ V_b,
                             const float* __restrict__ H_W, const float* __restrict__ H_b,
                             const float* __restrict__ Z_W, const float* __restrict__ Z_b,
                             const float* __restrict__ F_W,
                             _Float16* __restrict__ ws) {
    int b = blockIdx.x;
    int l = threadIdx.x;
    if (b == 44) {
        float* Fp = (float*)(ws + 22528);
        Fp[l] = (l < HID) ? F_W[l] : 0.f;
        return;
    }
    int g = l >> 4, cl = l & 15;
    half8 h;
    if (b < 12) {
        int m = b >> 2, nt = b & 3;
        const float* W = (m == 0) ? U_W : (m == 1) ? V_W : H_W;
        const float* B = (m == 0) ? U_b : (m == 1) ? V_b : H_b;
        int c = cl + 16 * nt;
        #pragma unroll
        for (int v = 0; v < 8; ++v) {
            int k = 8 * g + v;
            float x = 0.f;
            if (k < 12 && c < HID) { x = W[k * HID + c]; if (k == 1) x += B[c]; }
            h[v] = (_Float16)(x * KSC);
        }
    } else {
        int zb = b - 12;
        int li = zb >> 3, nt = (zb >> 1) & 3, ks = zb & 1;
        int c = cl + 16 * nt;
        #pragma unroll
        for (int v = 0; v < 8; ++v) {
            int k = ks * 32 + 8 * g + v;
            float x = 0.f;
            if (c < HID) {
                if (k < HID)       x = Z_W[li * (HID * HID) + k * HID + c];
                else if (k == HID) x = Z_b[li * HID + c];   // bias row (input feature 50 == 1.0)
            }
            h[v] = (_Float16)(x * KSC);
        }
    }
    *(half8*)(ws + (size_t)b * 512 + (size_t)l * 8) = h;
}

// ---------- main: persistent-lite; 1 block = 2 waves (8 KB LDS); 4 chunks of 64 pts ----------
// Transposed GEMMs: D = Wfrag(A) x Xfrag(B); D[feature=4g+r (+16ns)][point=cl].
// Inter-layer tile: per (wave,st) 16 cols (points) x 32 words (feature pairs),
// word p at column cl stored at word idx  cl*32 + (p ^ ((cl&7)<<2)).
__global__ __launch_bounds__(128, 3) void mlp_mfma(
        const float* __restrict__ X, const _Float16* __restrict__ ws,
        const float* __restrict__ F_b, float* __restrict__ out, int nchunk) {
    __shared__ __align__(16) unsigned int tile[2][2][512];   // 8 KB
    const int tid = threadIdx.x;
    const int wave = tid >> 6, l = tid & 63;
    const int g = l >> 4, cl = l & 15;
    const half8* __restrict__ wsv = (const half8*)ws;
    const float* __restrict__ Fp = (const float*)(ws + 22528);

    const int S = (cl & 7) << 2;
    int ow[4], orx[2];
    #pragma unroll
    for (int ns = 0; ns < 4; ++ns) ow[ns] = ((8 * ns + 2 * g) ^ S) + cl * 32;
    orx[0] = ((4 * g) ^ S) + cl * 32;
    orx[1] = ((16 + 4 * g) ^ S) + cl * 32;

    const float fb = F_b[0];

    #pragma unroll 1
    for (int chunk = 0; chunk < nchunk; ++chunk) {
        const int pbase = (blockIdx.x * nchunk + chunk) * 64 + wave * 32;

        // ---- Fourier embedding B-frags: lane holds Xe[point=cl][k=8g+v] ----
        half8 axe[2];
        #pragma unroll
        for (int st = 0; st < 2; ++st) {
            int p = pbase + st * 16 + cl;
            float2 xv = *(const float2*)(X + 2 * p);
            float t = xv.x, xs = xv.y;
            // sin/cos(pi/2 * xs) via HW units: input in revolutions = fract(xs/4)
            float rv = __builtin_amdgcn_fractf(xs * 0.25f);
            float s1 = __builtin_amdgcn_sinf(rv);
            float c1 = __builtin_amdgcn_cosf(rv);
            float cc[5], ss[5];
            cc[0] = c1; ss[0] = s1;
            #pragma unroll
            for (int m = 1; m < 5; ++m) {
                cc[m] = cc[m - 1] * c1 - ss[m - 1] * s1;
                ss[m] = ss[m - 1] * c1 + cc[m - 1] * s1;
            }
            float e0[8] = {t, 1.f, cc[0], cc[1], cc[2], cc[3], cc[4], ss[0]};
            float e1[8] = {ss[1], ss[2], ss[3], ss[4], 0.f, 0.f, 0.f, 0.f};
            half8 a;
            #pragma unroll
            for (int v = 0; v < 8; ++v) {
                float x = (g == 0) ? e0[v] : (g == 1) ? e1[v] : 0.f;
                a[v] = (_Float16)x;
            }
            axe[st] = a;
        }

        // ---- UVH stage: keep packed V and M = -2*(V-U); H -> LDS tiles ----
        // gate identity: U + tanh(s)*(V-U) = V + r*M  with r = sigr(acc)
        half2v Vh[2][4][2], Mh[2][4][2];
        #pragma unroll
        for (int ns = 0; ns < 4; ++ns) {
            half8 wU = wsv[(0 * 4 + ns) * 64 + l];
            half8 wV = wsv[(1 * 4 + ns) * 64 + l];
            half8 wH = wsv[(2 * 4 + ns) * 64 + l];
            #pragma unroll
            for (int st = 0; st < 2; ++st) {
                f32x4 z4 = {0.f, 0.f, 0.f, 0.f};
                f32x4 aU = __builtin_amdgcn_mfma_f32_16x16x32_f16(wU, axe[st], z4, 0, 0, 0);
                f32x4 aV = __builtin_amdgcn_mfma_f32_16x16x32_f16(wV, axe[st], z4, 0, 0, 0);
                f32x4 aH = __builtin_amdgcn_mfma_f32_16x16x32_f16(wH, axe[st], z4, 0, 0, 0);
                unsigned int* tb = &tile[wave][st][0];
                if (ns < 3) {
                    float rU0 = sigr(aU[0]), rU1 = sigr(aU[1]), rU2 = sigr(aU[2]), rU3 = sigr(aU[3]);
                    float rV0 = sigr(aV[0]), rV1 = sigr(aV[1]), rV2 = sigr(aV[2]), rV3 = sigr(aV[3]);
                    float rH0 = sigr(aH[0]), rH1 = sigr(aH[1]), rH2 = sigr(aH[2]), rH3 = sigr(aH[3]);
                    // V = 1-2rV ; M = -2(V-U) = 4(rV-rU) ; H = 1-2rH   (f32, then pack)
                    float v0 = fmaf(-2.f, rV0, 1.f), v1 = fmaf(-2.f, rV1, 1.f);
                    float v2 = fmaf(-2.f, rV2, 1.f), v3 = fmaf(-2.f, rV3, 1.f);
                    float m0 = (rV0 - rU0) * 4.f, m1 = (rV1 - rU1) * 4.f;
                    float m2 = (rV2 - rU2) * 4.f, m3 = (rV3 - rU3) * 4.f;
                    float h0 = fmaf(-2.f, rH0, 1.f), h1 = fmaf(-2.f, rH1, 1.f);
                    float h2 = fmaf(-2.f, rH2, 1.f), h3 = fmaf(-2.f, rH3, 1.f);
                    Vh[st][ns][0] = pk2h(v0, v1);  Vh[st][ns][1] = pk2h(v2, v3);
                    Mh[st][ns][0] = pk2h(m0, m1);  Mh[st][ns][1] = pk2h(m2, m3);
                    uint2v hw;
                    hw[0] = h2u(pk2h(h0, h1));
                    hw[1] = h2u(pk2h(h2, h3));
                    *(uint2v*)(tb + ow[ns]) = hw;
                } else {          // features 48,49 real; 50 = bias lane (1.0); 51+ dead
                    float rU0 = sigr(aU[0]), rU1 = sigr(aU[1]);
                    float rV0 = sigr(aV[0]), rV1 = sigr(aV[1]);
                    float rH0 = sigr(aH[0]), rH1 = sigr(aH[1]);
                    float v0 = fmaf(-2.f, rV0, 1.f), v1 = fmaf(-2.f, rV1, 1.f);
                    float m0 = (rV0 - rU0) * 4.f, m1 = (rV1 - rU1) * 4.f;
                    float h0 = fmaf(-2.f, rH0, 1.f), h1 = fmaf(-2.f, rH1, 1.f);
                    Vh[st][3][0] = pk2h(v0, v1);  Vh[st][3][1] = pk2h(0.f, 0.f);
                    Mh[st][3][0] = pk2h(m0, m1);  Mh[st][3][1] = pk2h(0.f, 0.f);
                    uint2v hw;
                    hw[0] = h2u(pk2h(h0, h1));
                    hw[1] = 0x00003C00u;                    // (1.0h, 0.0h)
                    *(uint2v*)(tb + ow[3]) = hw;
                }
            }
        }

        // ---- Z layers 0..2: MFMA -> r -> one pk_fma gate -> write back ----
        #pragma unroll
        for (int li = 0; li < 3; ++li) {
            half8 wz[4][2];
            #pragma unroll
            for (int ns = 0; ns < 4; ++ns)
                #pragma unroll
                for (int ks = 0; ks < 2; ++ks)
                    wz[ns][ks] = wsv[768 + ((li * 4 + ns) * 2 + ks) * 64 + l];
            #pragma unroll
            for (int st = 0; st < 2; ++st) {
                unsigned int* tb = &tile[wave][st][0];
                uint4v q0 = *(const uint4v*)(tb + orx[0]);
                uint4v q1 = *(const uint4v*)(tb + orx[1]);
                half8 b0 = __builtin_bit_cast(half8, q0);
                half8 b1 = __builtin_bit_cast(half8, q1);
                #pragma unroll
                for (int ns = 0; ns < 4; ++ns) {
                    f32x4 z4 = {0.f, 0.f, 0.f, 0.f};
                    f32x4 acc = __builtin_amdgcn_mfma_f32_16x16x32_f16(wz[ns][0], b0, z4, 0, 0, 0);
                    acc = __builtin_amdgcn_mfma_f32_16x16x32_f16(wz[ns][1], b1, acc, 0, 0, 0);
                    half2v r01 = pk2h(sigr(acc[0]), sigr(acc[1]));
                    half2v g01 = r01 * Mh[st][ns][0] + Vh[st][ns][0];   // v_pk_fma_f16
                    uint2v gw;
                    gw[0] = h2u(g01);
                    if (ns < 3) {
                        half2v r23 = pk2h(sigr(acc[2]), sigr(acc[3]));
                        half2v g23 = r23 * Mh[st][ns][1] + Vh[st][ns][1];
                        gw[1] = h2u(g23);
                    } else {
                        gw[1] = 0x00003C00u;                // keep bias lane = 1.0
                    }
                    *(uint2v*)(tb + ow[ns]) = gw;
                }
            }
        }

        // ---- last Z layer fused with F projection (f32 gate, no LDS write-back) ----
        {
            half8 wz[4][2];
            #pragma unroll
            for (int ns = 0; ns < 4; ++ns)
                #pragma unroll
                for (int ks = 0; ks < 2; ++ks)
                    wz[ns][ks] = wsv[768 + ((3 * 4 + ns) * 2 + ks) * 64 + l];
            #pragma unroll
            for (int st = 0; st < 2; ++st) {
                unsigned int* tb = &tile[wave][st][0];
                uint4v q0 = *(const uint4v*)(tb + orx[0]);
                uint4v q1 = *(const uint4v*)(tb + orx[1]);
                half8 b0 = __builtin_bit_cast(half8, q0);
                half8 b1 = __builtin_bit_cast(half8, q1);
                float s = 0.f;
                #pragma unroll
                for (int ns = 0; ns < 4; ++ns) {
                    f32x4 z4 = {0.f, 0.f, 0.f, 0.f};
                    f32x4 acc = __builtin_amdgcn_mfma_f32_16x16x32_f16(wz[ns][0], b0, z4, 0, 0, 0);
                    acc = __builtin_amdgcn_mfma_f32_16x16x32_f16(wz[ns][1], b1, acc, 0, 0, 0);
                    f32x4 fw = *(const f32x4*)(Fp + 16 * ns + 4 * g);
                    const int RMAX = (ns < 3) ? 4 : 2;   // padded features have fw == 0
                    #pragma unroll
                    for (int r = 0; r < RMAX; ++r) {
                        float rr = sigr(acc[r]);
                        half2v m2 = Mh[st][ns][r >> 1];
                        half2v vv = Vh[st][ns][r >> 1];
                        float gg = fmaf(rr, (float)m2[r & 1], (float)vv[r & 1]);
                        s = fmaf(gg, fw[r], s);
                    }
                }
                s += __shfl_xor(s, 16);
                s += __shfl_xor(s, 32);
                if (l < 16) out[pbase + st * 16 + cl] = s + fb;
            }
        }
    }
}

extern "C" void kernel_launch(void* const* d_in, const int* in_sizes, int n_in,
                              void* d_out, int out_size, void* d_ws, size_t ws_size,
                              hipStream_t stream) {
    const float* X   = (const float*)d_in[0];
    const float* U_W = (const float*)d_in[1];
    const float* U_b = (const float*)d_in[2];
    const float* V_W = (const float*)d_in[3];
    const float* V_b = (const float*)d_in[4];
    const float* H_W = (const float*)d_in[5];
    const float* H_b = (const float*)d_in[6];
    const float* Z_W = (const float*)d_in[7];
    const float* Z_b = (const float*)d_in[8];
    const float* F_W = (const float*)d_in[9];
    const float* F_b = (const float*)d_in[10];
    float* out = (float*)d_out;
    _Float16* ws16 = (_Float16*)d_ws;

    int N = in_sizes[0] / 2;              // 1048576
    prep_weights<<<45, 64, 0, stream>>>(U_W, U_b, V_W, V_b, H_W, H_b, Z_W, Z_b, F_W, ws16);
    const int blocks = 4096;              // persistent-lite: waves live 4x longer
    int nchunk = N / (blocks * 64);       // 4 chunks of 64 points per block
    mlp_mfma<<<blocks, 128, 0, stream>>>(X, ws16, F_b, out, nchunk);
}

// Round 10
// 96.217 us; speedup vs baseline: 1.7520x; 1.7520x over previous
//
#include <hip/hip_runtime.h>

typedef _Float16 half8 __attribute__((ext_vector_type(8)));
typedef _Float16 half2v __attribute__((ext_vector_type(2)));
typedef float f32x4 __attribute__((ext_vector_type(4)));
typedef unsigned int uint2v __attribute__((ext_vector_type(2)));
typedef unsigned int uint4v __attribute__((ext_vector_type(4)));

#define HID 50
#define KSC 2.8853900817779268f   // 2*log2(e), folded into all W/b at prep

// r = 1/(1 + 2^a)  where a = 2*log2(e)*s  =>  tanh(s) = 1 - 2r
__device__ __forceinline__ float sigr(float a) {
    return __builtin_amdgcn_rcpf(1.0f + __builtin_amdgcn_exp2f(a));
}
__device__ __forceinline__ half2v pk2h(float a, float b) {
    return __builtin_bit_cast(half2v, __builtin_amdgcn_cvt_pkrtz(a, b));
}
__device__ __forceinline__ unsigned int h2u(half2v h) {
    return __builtin_bit_cast(unsigned int, h);
}

// ---------- weight prep: 45 blocks x 64 threads ----------
// half8-block b, lane l (g=l>>4, cl=l&15), elem v -> W[k = 8g+v (+32ks)][col = cl+16nt]
//   b in [0,12):  UVH  b = m*4 + nt           (K=32 padded from 12, bias folded at k==1)
//   b in [12,44): Z    b = 12 + (li*4+nt)*2 + ks  (K=64 padded from 50, bias row at k==50)
//   block 44: F_W padded to 64 floats at f16-offset 22528
// All UVH/Z weights and biases pre-scaled by KSC (they only feed tanh).
__global__ void prep_weights(const float* __restrict__ U_W, const float* __restrict__ U_b,
                             const float* __restrict__ V_W, const float* __restrict__ V_b,
                             const float* __restrict__ H_W, const float* __restrict__ H_b,
                             const float* __restrict__ Z_W, const float* __restrict__ Z_b,
                             const float* __restrict__ F_W,
                             _Float16* __restrict__ ws) {
    int b = blockIdx.x;
    int l = threadIdx.x;
    if (b == 44) {
        float* Fp = (float*)(ws + 22528);
        Fp[l] = (l < HID) ? F_W[l] : 0.f;
        return;
    }
    int g = l >> 4, cl = l & 15;
    half8 h;
    if (b < 12) {
        int m = b >> 2, nt = b & 3;
        const float* W = (m == 0) ? U_W : (m == 1) ? V_W : H_W;
        const float* B = (m == 0) ? U_b : (m == 1) ? V_b : H_b;
        int c = cl + 16 * nt;
        #pragma unroll
        for (int v = 0; v < 8; ++v) {
            int k = 8 * g + v;
            float x = 0.f;
            if (k < 12 && c < HID) { x = W[k * HID + c]; if (k == 1) x += B[c]; }
            h[v] = (_Float16)(x * KSC);
        }
    } else {
        int zb = b - 12;
        int li = zb >> 3, nt = (zb >> 1) & 3, ks = zb & 1;
        int c = cl + 16 * nt;
        #pragma unroll
        for (int v = 0; v < 8; ++v) {
            int k = ks * 32 + 8 * g + v;
            float x = 0.f;
            if (c < HID) {
                if (k < HID)       x = Z_W[li * (HID * HID) + k * HID + c];
                else if (k == HID) x = Z_b[li * HID + c];   // bias row (input feature 50 == 1.0)
            }
            h[v] = (_Float16)(x * KSC);
        }
    }
    *(half8*)(ws + (size_t)b * 512 + (size_t)l * 8) = h;
}

// ---------- main: 1 block = 2 waves (8 KB LDS), 1 wave = 32 points ----------
// Transposed GEMMs: D = Wfrag(A) x Xfrag(B); D[feature=4g+r (+16ns)][point=cl].
// Inter-layer tile: per (wave,st) 16 cols (points) x 32 words (feature pairs),
// word p at column cl stored at word idx  cl*32 + (p ^ ((cl&7)<<2)).
// launch_bounds(128,4): cap unified VGPR+AGPR file at 128 -> 4 waves/SIMD
// (R9 analysis: ~160 total regs -> 3.2 waves/SIMD = the 40% occupancy cap).
__global__ __launch_bounds__(128, 4) void mlp_mfma(
        const float* __restrict__ X, const _Float16* __restrict__ ws,
        const float* __restrict__ F_b, float* __restrict__ out) {
    __shared__ __align__(16) unsigned int tile[2][2][512];   // 8 KB
    const int tid = threadIdx.x;
    const int wave = tid >> 6, l = tid & 63;
    const int g = l >> 4, cl = l & 15;
    const int pbase = blockIdx.x * 64 + wave * 32;
    const half8* __restrict__ wsv = (const half8*)ws;
    const float* __restrict__ Fp = (const float*)(ws + 22528);

    const int S = (cl & 7) << 2;
    int ow[4], orx[2];
    #pragma unroll
    for (int ns = 0; ns < 4; ++ns) ow[ns] = ((8 * ns + 2 * g) ^ S) + cl * 32;
    orx[0] = ((4 * g) ^ S) + cl * 32;
    orx[1] = ((16 + 4 * g) ^ S) + cl * 32;

    // ---- Fourier embedding B-frags: lane holds Xe[point=cl][k=8g+v] ----
    half8 axe[2];
    #pragma unroll
    for (int st = 0; st < 2; ++st) {
        int p = pbase + st * 16 + cl;
        float2 xv = *(const float2*)(X + 2 * p);
        float t = xv.x, xs = xv.y;
        // sin/cos(pi/2 * xs) via HW units: input in revolutions = fract(xs/4)
        float rv = __builtin_amdgcn_fractf(xs * 0.25f);
        float s1 = __builtin_amdgcn_sinf(rv);
        float c1 = __builtin_amdgcn_cosf(rv);
        float cc[5], ss[5];
        cc[0] = c1; ss[0] = s1;
        #pragma unroll
        for (int m = 1; m < 5; ++m) {
            cc[m] = cc[m - 1] * c1 - ss[m - 1] * s1;
            ss[m] = ss[m - 1] * c1 + cc[m - 1] * s1;
        }
        float e0[8] = {t, 1.f, cc[0], cc[1], cc[2], cc[3], cc[4], ss[0]};
        float e1[8] = {ss[1], ss[2], ss[3], ss[4], 0.f, 0.f, 0.f, 0.f};
        half8 a;
        #pragma unroll
        for (int v = 0; v < 8; ++v) {
            float x = (g == 0) ? e0[v] : (g == 1) ? e1[v] : 0.f;
            a[v] = (_Float16)x;
        }
        axe[st] = a;
    }

    // ---- UVH stage: keep packed V and M = -2*(V-U); H -> LDS tiles ----
    // gate identity: U + tanh(s)*(V-U) = V + r*M  with r = sigr(acc)
    half2v Vh[2][4][2], Mh[2][4][2];
    #pragma unroll
    for (int ns = 0; ns < 4; ++ns) {
        half8 wU = wsv[(0 * 4 + ns) * 64 + l];
        half8 wV = wsv[(1 * 4 + ns) * 64 + l];
        half8 wH = wsv[(2 * 4 + ns) * 64 + l];
        #pragma unroll
        for (int st = 0; st < 2; ++st) {
            f32x4 z4 = {0.f, 0.f, 0.f, 0.f};
            f32x4 aU = __builtin_amdgcn_mfma_f32_16x16x32_f16(wU, axe[st], z4, 0, 0, 0);
            f32x4 aV = __builtin_amdgcn_mfma_f32_16x16x32_f16(wV, axe[st], z4, 0, 0, 0);
            f32x4 aH = __builtin_amdgcn_mfma_f32_16x16x32_f16(wH, axe[st], z4, 0, 0, 0);
            unsigned int* tb = &tile[wave][st][0];
            if (ns < 3) {
                float rU0 = sigr(aU[0]), rU1 = sigr(aU[1]), rU2 = sigr(aU[2]), rU3 = sigr(aU[3]);
                float rV0 = sigr(aV[0]), rV1 = sigr(aV[1]), rV2 = sigr(aV[2]), rV3 = sigr(aV[3]);
                float rH0 = sigr(aH[0]), rH1 = sigr(aH[1]), rH2 = sigr(aH[2]), rH3 = sigr(aH[3]);
                // V = 1-2rV ; M = -2(V-U) = 4(rV-rU) ; H = 1-2rH   (f32, then pack)
                float v0 = fmaf(-2.f, rV0, 1.f), v1 = fmaf(-2.f, rV1, 1.f);
                float v2 = fmaf(-2.f, rV2, 1.f), v3 = fmaf(-2.f, rV3, 1.f);
                float m0 = (rV0 - rU0) * 4.f, m1 = (rV1 - rU1) * 4.f;
                float m2 = (rV2 - rU2) * 4.f, m3 = (rV3 - rU3) * 4.f;
                float h0 = fmaf(-2.f, rH0, 1.f), h1 = fmaf(-2.f, rH1, 1.f);
                float h2 = fmaf(-2.f, rH2, 1.f), h3 = fmaf(-2.f, rH3, 1.f);
                Vh[st][ns][0] = pk2h(v0, v1);  Vh[st][ns][1] = pk2h(v2, v3);
                Mh[st][ns][0] = pk2h(m0, m1);  Mh[st][ns][1] = pk2h(m2, m3);
                uint2v hw;
                hw[0] = h2u(pk2h(h0, h1));
                hw[1] = h2u(pk2h(h2, h3));
                *(uint2v*)(tb + ow[ns]) = hw;
            } else {          // features 48,49 real; 50 = bias lane (1.0); 51+ dead
                float rU0 = sigr(aU[0]), rU1 = sigr(aU[1]);
                float rV0 = sigr(aV[0]), rV1 = sigr(aV[1]);
                float rH0 = sigr(aH[0]), rH1 = sigr(aH[1]);
                float v0 = fmaf(-2.f, rV0, 1.f), v1 = fmaf(-2.f, rV1, 1.f);
                float m0 = (rV0 - rU0) * 4.f, m1 = (rV1 - rU1) * 4.f;
                float h0 = fmaf(-2.f, rH0, 1.f), h1 = fmaf(-2.f, rH1, 1.f);
                Vh[st][3][0] = pk2h(v0, v1);  Vh[st][3][1] = pk2h(0.f, 0.f);
                Mh[st][3][0] = pk2h(m0, m1);  Mh[st][3][1] = pk2h(0.f, 0.f);
                uint2v hw;
                hw[0] = h2u(pk2h(h0, h1));
                hw[1] = 0x00003C00u;                    // (1.0h, 0.0h)
                *(uint2v*)(tb + ow[3]) = hw;
            }
        }
    }

    // ---- Z layers 0..2: MFMA -> r -> one pk_fma gate -> write back ----
    #pragma unroll
    for (int li = 0; li < 3; ++li) {
        half8 wz[4][2];
        #pragma unroll
        for (int ns = 0; ns < 4; ++ns)
            #pragma unroll
            for (int ks = 0; ks < 2; ++ks)
                wz[ns][ks] = wsv[768 + ((li * 4 + ns) * 2 + ks) * 64 + l];
        #pragma unroll
        for (int st = 0; st < 2; ++st) {
            unsigned int* tb = &tile[wave][st][0];
            uint4v q0 = *(const uint4v*)(tb + orx[0]);
            uint4v q1 = *(const uint4v*)(tb + orx[1]);
            half8 b0 = __builtin_bit_cast(half8, q0);
            half8 b1 = __builtin_bit_cast(half8, q1);
            #pragma unroll
            for (int ns = 0; ns < 4; ++ns) {
                f32x4 z4 = {0.f, 0.f, 0.f, 0.f};
                f32x4 acc = __builtin_amdgcn_mfma_f32_16x16x32_f16(wz[ns][0], b0, z4, 0, 0, 0);
                acc = __builtin_amdgcn_mfma_f32_16x16x32_f16(wz[ns][1], b1, acc, 0, 0, 0);
                half2v r01 = pk2h(sigr(acc[0]), sigr(acc[1]));
                half2v g01 = r01 * Mh[st][ns][0] + Vh[st][ns][0];   // v_pk_fma_f16
                uint2v gw;
                gw[0] = h2u(g01);
                if (ns < 3) {
                    half2v r23 = pk2h(sigr(acc[2]), sigr(acc[3]));
                    half2v g23 = r23 * Mh[st][ns][1] + Vh[st][ns][1];
                    gw[1] = h2u(g23);
                } else {
                    gw[1] = 0x00003C00u;                // keep bias lane = 1.0
                }
                *(uint2v*)(tb + ow[ns]) = gw;
            }
        }
    }

    // ---- last Z layer fused with F projection (f32 gate, no LDS write-back) ----
    {
        half8 wz[4][2];
        #pragma unroll
        for (int ns = 0; ns < 4; ++ns)
            #pragma unroll
            for (int ks = 0; ks < 2; ++ks)
                wz[ns][ks] = wsv[768 + ((3 * 4 + ns) * 2 + ks) * 64 + l];
        float fb = F_b[0];
        #pragma unroll
        for (int st = 0; st < 2; ++st) {
            unsigned int* tb = &tile[wave][st][0];
            uint4v q0 = *(const uint4v*)(tb + orx[0]);
            uint4v q1 = *(const uint4v*)(tb + orx[1]);
            half8 b0 = __builtin_bit_cast(half8, q0);
            half8 b1 = __builtin_bit_cast(half8, q1);
            float s = 0.f;
            #pragma unroll
            for (int ns = 0; ns < 4; ++ns) {
                f32x4 z4 = {0.f, 0.f, 0.f, 0.f};
                f32x4 acc = __builtin_amdgcn_mfma_f32_16x16x32_f16(wz[ns][0], b0, z4, 0, 0, 0);
                acc = __builtin_amdgcn_mfma_f32_16x16x32_f16(wz[ns][1], b1, acc, 0, 0, 0);
                f32x4 fw = *(const f32x4*)(Fp + 16 * ns + 4 * g);
                const int RMAX = (ns < 3) ? 4 : 2;   // padded features have fw == 0
                #pragma unroll
                for (int r = 0; r < RMAX; ++r) {
                    float rr = sigr(acc[r]);
                    half2v m2 = Mh[st][ns][r >> 1];
                    half2v vv = Vh[st][ns][r >> 1];
                    float gg = fmaf(rr, (float)m2[r & 1], (float)vv[r & 1]);
                    s = fmaf(gg, fw[r], s);
                }
            }
            s += __shfl_xor(s, 16);
            s += __shfl_xor(s, 32);
            if (l < 16) out[pbase + st * 16 + cl] = s + fb;
        }
    }
}

extern "C" void kernel_launch(void* const* d_in, const int* in_sizes, int n_in,
                              void* d_out, int out_size, void* d_ws, size_t ws_size,
                              hipStream_t stream) {
    const float* X   = (const float*)d_in[0];
    const float* U_W = (const float*)d_in[1];
    const float* U_b = (const float*)d_in[2];
    const float* V_W = (const float*)d_in[3];
    const float* V_b = (const float*)d_in[4];
    const float* H_W = (const float*)d_in[5];
    const float* H_b = (const float*)d_in[6];
    const float* Z_W = (const float*)d_in[7];
    const float* Z_b = (const float*)d_in[8];
    const float* F_W = (const float*)d_in[9];
    const float* F_b = (const float*)d_in[10];
    float* out = (float*)d_out;
    _Float16* ws16 = (_Float16*)d_ws;

    int N = in_sizes[0] / 2;          // 1048576; 64 points per block (2 waves)
    prep_weights<<<45, 64, 0, stream>>>(U_W, U_b, V_W, V_b, H_W, H_b, Z_W, Z_b, F_W, ws16);
    int blocks = N / 64;
    mlp_mfma<<<blocks, 128, 0, stream>>>(X, ws16, F_b, out);
}

// Round 11
// 95.214 us; speedup vs baseline: 1.7705x; 1.0105x over previous
//
#include <hip/hip_runtime.h>

typedef _Float16 half8 __attribute__((ext_vector_type(8)));
typedef _Float16 half2v __attribute__((ext_vector_type(2)));
typedef float f32x4 __attribute__((ext_vector_type(4)));
typedef unsigned int uint2v __attribute__((ext_vector_type(2)));
typedef unsigned int uint4v __attribute__((ext_vector_type(4)));

#define HID 50
#define KSC 2.8853900817779268f   // 2*log2(e), folded into all W/b at prep

// r = 1/(1 + 2^a)  where a = 2*log2(e)*s  =>  tanh(s) = 1 - 2r
__device__ __forceinline__ float sigr(float a) {
    return __builtin_amdgcn_rcpf(1.0f + __builtin_amdgcn_exp2f(a));
}
__device__ __forceinline__ half2v pk2h(float a, float b) {
    return __builtin_bit_cast(half2v, __builtin_amdgcn_cvt_pkrtz(a, b));
}
__device__ __forceinline__ unsigned int h2u(half2v h) {
    return __builtin_bit_cast(unsigned int, h);
}

// ---------- weight prep: 45 blocks x 64 threads ----------
// half8-block b, lane l (g=l>>4, cl=l&15), elem v -> W[k = 8g+v (+32ks)][col = cl+16nt]
//   b in [0,12):  UVH  b = m*4 + nt           (K=32 padded from 12, bias folded at k==1)
//   b in [12,44): Z    b = 12 + (li*4+nt)*2 + ks  (K=64 padded from 50, bias row at k==50)
//   block 44: F_W padded to 64 floats at f16-offset 22528
// All UVH/Z weights and biases pre-scaled by KSC (they only feed tanh).
__global__ void prep_weights(const float* __restrict__ U_W, const float* __restrict__ U_b,
                             const float* __restrict__ V_W, const float* __restrict__ V_b,
                             const float* __restrict__ H_W, const float* __restrict__ H_b,
                             const float* __restrict__ Z_W, const float* __restrict__ Z_b,
                             const float* __restrict__ F_W,
                             _Float16* __restrict__ ws) {
    int b = blockIdx.x;
    int l = threadIdx.x;
    if (b == 44) {
        float* Fp = (float*)(ws + 22528);
        Fp[l] = (l < HID) ? F_W[l] : 0.f;
        return;
    }
    int g = l >> 4, cl = l & 15;
    half8 h;
    if (b < 12) {
        int m = b >> 2, nt = b & 3;
        const float* W = (m == 0) ? U_W : (m == 1) ? V_W : H_W;
        const float* B = (m == 0) ? U_b : (m == 1) ? V_b : H_b;
        int c = cl + 16 * nt;
        #pragma unroll
        for (int v = 0; v < 8; ++v) {
            int k = 8 * g + v;
            float x = 0.f;
            if (k < 12 && c < HID) { x = W[k * HID + c]; if (k == 1) x += B[c]; }
            h[v] = (_Float16)(x * KSC);
        }
    } else {
        int zb = b - 12;
        int li = zb >> 3, nt = (zb >> 1) & 3, ks = zb & 1;
        int c = cl + 16 * nt;
        #pragma unroll
        for (int v = 0; v < 8; ++v) {
            int k = ks * 32 + 8 * g + v;
            float x = 0.f;
            if (c < HID) {
                if (k < HID)       x = Z_W[li * (HID * HID) + k * HID + c];
                else if (k == HID) x = Z_b[li * HID + c];   // bias row (input feature 50 == 1.0)
            }
            h[v] = (_Float16)(x * KSC);
        }
    }
    *(half8*)(ws + (size_t)b * 512 + (size_t)l * 8) = h;
}

// ---------- main: 1 block = 2 waves (16 KB LDS), 1 wave = 64 points (4 subtiles) ----------
// Transposed GEMMs: D = Wfrag(A) x Xfrag(B); D[feature=4g+r (+16ns)][point=cl].
// Inter-layer tile: per (wave,st) 16 cols (points) x 32 words (feature pairs),
// word p at column cl stored at word idx  cl*32 + (p ^ ((cl&7)<<2)).
// 4 subtiles/wave: 4 independent MFMA->sigr->gate chains for ILP (R10: waves
// stall 74% on deps; occupancy is pinned ~3.2/SIMD regardless of resources).
__global__ __launch_bounds__(128, 3) void mlp_mfma(
        const float* __restrict__ X, const _Float16* __restrict__ ws,
        const float* __restrict__ F_b, float* __restrict__ out) {
    __shared__ __align__(16) unsigned int tile[2][4][512];   // 16 KB
    const int tid = threadIdx.x;
    const int wave = tid >> 6, l = tid & 63;
    const int g = l >> 4, cl = l & 15;
    const int pbase = blockIdx.x * 128 + wave * 64;
    const half8* __restrict__ wsv = (const half8*)ws;
    const float* __restrict__ Fp = (const float*)(ws + 22528);

    const int S = (cl & 7) << 2;
    int ow[4], orx[2];
    #pragma unroll
    for (int ns = 0; ns < 4; ++ns) ow[ns] = ((8 * ns + 2 * g) ^ S) + cl * 32;
    orx[0] = ((4 * g) ^ S) + cl * 32;
    orx[1] = ((16 + 4 * g) ^ S) + cl * 32;

    // ---- Fourier embedding B-frags: lane holds Xe[point=cl][k=8g+v] ----
    half8 axe[4];
    #pragma unroll
    for (int st = 0; st < 4; ++st) {
        int p = pbase + st * 16 + cl;
        float2 xv = *(const float2*)(X + 2 * p);
        float t = xv.x, xs = xv.y;
        // sin/cos(pi/2 * xs) via HW units: input in revolutions = fract(xs/4)
        float rv = __builtin_amdgcn_fractf(xs * 0.25f);
        float s1 = __builtin_amdgcn_sinf(rv);
        float c1 = __builtin_amdgcn_cosf(rv);
        float cc[5], ss[5];
        cc[0] = c1; ss[0] = s1;
        #pragma unroll
        for (int m = 1; m < 5; ++m) {
            cc[m] = cc[m - 1] * c1 - ss[m - 1] * s1;
            ss[m] = ss[m - 1] * c1 + cc[m - 1] * s1;
        }
        float e0[8] = {t, 1.f, cc[0], cc[1], cc[2], cc[3], cc[4], ss[0]};
        float e1[8] = {ss[1], ss[2], ss[3], ss[4], 0.f, 0.f, 0.f, 0.f};
        half8 a;
        #pragma unroll
        for (int v = 0; v < 8; ++v) {
            float x = (g == 0) ? e0[v] : (g == 1) ? e1[v] : 0.f;
            a[v] = (_Float16)x;
        }
        axe[st] = a;
    }

    // ---- UVH stage: keep packed V and M = -2*(V-U); H -> LDS tiles ----
    // gate identity: U + tanh(s)*(V-U) = V + r*M  with r = sigr(acc)
    half2v Vh[4][4][2], Mh[4][4][2];
    #pragma unroll
    for (int ns = 0; ns < 4; ++ns) {
        half8 wU = wsv[(0 * 4 + ns) * 64 + l];
        half8 wV = wsv[(1 * 4 + ns) * 64 + l];
        half8 wH = wsv[(2 * 4 + ns) * 64 + l];
        #pragma unroll
        for (int st = 0; st < 4; ++st) {
            f32x4 z4 = {0.f, 0.f, 0.f, 0.f};
            f32x4 aU = __builtin_amdgcn_mfma_f32_16x16x32_f16(wU, axe[st], z4, 0, 0, 0);
            f32x4 aV = __builtin_amdgcn_mfma_f32_16x16x32_f16(wV, axe[st], z4, 0, 0, 0);
            f32x4 aH = __builtin_amdgcn_mfma_f32_16x16x32_f16(wH, axe[st], z4, 0, 0, 0);
            unsigned int* tb = &tile[wave][st][0];
            if (ns < 3) {
                float rU0 = sigr(aU[0]), rU1 = sigr(aU[1]), rU2 = sigr(aU[2]), rU3 = sigr(aU[3]);
                float rV0 = sigr(aV[0]), rV1 = sigr(aV[1]), rV2 = sigr(aV[2]), rV3 = sigr(aV[3]);
                float rH0 = sigr(aH[0]), rH1 = sigr(aH[1]), rH2 = sigr(aH[2]), rH3 = sigr(aH[3]);
                // V = 1-2rV ; M = -2(V-U) = 4(rV-rU) ; H = 1-2rH   (f32, then pack)
                float v0 = fmaf(-2.f, rV0, 1.f), v1 = fmaf(-2.f, rV1, 1.f);
                float v2 = fmaf(-2.f, rV2, 1.f), v3 = fmaf(-2.f, rV3, 1.f);
                float m0 = (rV0 - rU0) * 4.f, m1 = (rV1 - rU1) * 4.f;
                float m2 = (rV2 - rU2) * 4.f, m3 = (rV3 - rU3) * 4.f;
                float h0 = fmaf(-2.f, rH0, 1.f), h1 = fmaf(-2.f, rH1, 1.f);
                float h2 = fmaf(-2.f, rH2, 1.f), h3 = fmaf(-2.f, rH3, 1.f);
                Vh[st][ns][0] = pk2h(v0, v1);  Vh[st][ns][1] = pk2h(v2, v3);
                Mh[st][ns][0] = pk2h(m0, m1);  Mh[st][ns][1] = pk2h(m2, m3);
                uint2v hw;
                hw[0] = h2u(pk2h(h0, h1));
                hw[1] = h2u(pk2h(h2, h3));
                *(uint2v*)(tb + ow[ns]) = hw;
            } else {          // features 48,49 real; 50 = bias lane (1.0); 51+ dead
                float rU0 = sigr(aU[0]), rU1 = sigr(aU[1]);
                float rV0 = sigr(aV[0]), rV1 = sigr(aV[1]);
                float rH0 = sigr(aH[0]), rH1 = sigr(aH[1]);
                float v0 = fmaf(-2.f, rV0, 1.f), v1 = fmaf(-2.f, rV1, 1.f);
                float m0 = (rV0 - rU0) * 4.f, m1 = (rV1 - rU1) * 4.f;
                float h0 = fmaf(-2.f, rH0, 1.f), h1 = fmaf(-2.f, rH1, 1.f);
                Vh[st][3][0] = pk2h(v0, v1);  Vh[st][3][1] = pk2h(0.f, 0.f);
                Mh[st][3][0] = pk2h(m0, m1);  Mh[st][3][1] = pk2h(0.f, 0.f);
                uint2v hw;
                hw[0] = h2u(pk2h(h0, h1));
                hw[1] = 0x00003C00u;                    // (1.0h, 0.0h)
                *(uint2v*)(tb + ow[3]) = hw;
            }
        }
    }

    // ---- Z layers 0..2: MFMA -> r -> one pk_fma gate -> write back ----
    #pragma unroll
    for (int li = 0; li < 3; ++li) {
        half8 wz[4][2];
        #pragma unroll
        for (int ns = 0; ns < 4; ++ns)
            #pragma unroll
            for (int ks = 0; ks < 2; ++ks)
                wz[ns][ks] = wsv[768 + ((li * 4 + ns) * 2 + ks) * 64 + l];
        #pragma unroll
        for (int st = 0; st < 4; ++st) {
            unsigned int* tb = &tile[wave][st][0];
            uint4v q0 = *(const uint4v*)(tb + orx[0]);
            uint4v q1 = *(const uint4v*)(tb + orx[1]);
            half8 b0 = __builtin_bit_cast(half8, q0);
            half8 b1 = __builtin_bit_cast(half8, q1);
            #pragma unroll
            for (int ns = 0; ns < 4; ++ns) {
                f32x4 z4 = {0.f, 0.f, 0.f, 0.f};
                f32x4 acc = __builtin_amdgcn_mfma_f32_16x16x32_f16(wz[ns][0], b0, z4, 0, 0, 0);
                acc = __builtin_amdgcn_mfma_f32_16x16x32_f16(wz[ns][1], b1, acc, 0, 0, 0);
                half2v r01 = pk2h(sigr(acc[0]), sigr(acc[1]));
                half2v g01 = r01 * Mh[st][ns][0] + Vh[st][ns][0];   // v_pk_fma_f16
                uint2v gw;
                gw[0] = h2u(g01);
                if (ns < 3) {
                    half2v r23 = pk2h(sigr(acc[2]), sigr(acc[3]));
                    half2v g23 = r23 * Mh[st][ns][1] + Vh[st][ns][1];
                    gw[1] = h2u(g23);
                } else {
                    gw[1] = 0x00003C00u;                // keep bias lane = 1.0
                }
                *(uint2v*)(tb + ow[ns]) = gw;
            }
        }
    }

    // ---- last Z layer fused with F projection (f32 gate, no LDS write-back) ----
    {
        half8 wz[4][2];
        #pragma unroll
        for (int ns = 0; ns < 4; ++ns)
            #pragma unroll
            for (int ks = 0; ks < 2; ++ks)
                wz[ns][ks] = wsv[768 + ((3 * 4 + ns) * 2 + ks) * 64 + l];
        float fb = F_b[0];
        #pragma unroll
        for (int st = 0; st < 4; ++st) {
            unsigned int* tb = &tile[wave][st][0];
            uint4v q0 = *(const uint4v*)(tb + orx[0]);
            uint4v q1 = *(const uint4v*)(tb + orx[1]);
            half8 b0 = __builtin_bit_cast(half8, q0);
            half8 b1 = __builtin_bit_cast(half8, q1);
            float s = 0.f;
            #pragma unroll
            for (int ns = 0; ns < 4; ++ns) {
                f32x4 z4 = {0.f, 0.f, 0.f, 0.f};
                f32x4 acc = __builtin_amdgcn_mfma_f32_16x16x32_f16(wz[ns][0], b0, z4, 0, 0, 0);
                acc = __builtin_amdgcn_mfma_f32_16x16x32_f16(wz[ns][1], b1, acc, 0, 0, 0);
                f32x4 fw = *(const f32x4*)(Fp + 16 * ns + 4 * g);
                const int RMAX = (ns < 3) ? 4 : 2;   // padded features have fw == 0
                #pragma unroll
                for (int r = 0; r < RMAX; ++r) {
                    float rr = sigr(acc[r]);
                    half2v m2 = Mh[st][ns][r >> 1];
                    half2v vv = Vh[st][ns][r >> 1];
                    float gg = fmaf(rr, (float)m2[r & 1], (float)vv[r & 1]);
                    s = fmaf(gg, fw[r], s);
                }
            }
            s += __shfl_xor(s, 16);
            s += __shfl_xor(s, 32);
            if (l < 16) out[pbase + st * 16 + cl] = s + fb;
        }
    }
}

extern "C" void kernel_launch(void* const* d_in, const int* in_sizes, int n_in,
                              void* d_out, int out_size, void* d_ws, size_t ws_size,
                              hipStream_t stream) {
    const float* X   = (const float*)d_in[0];
    const float* U_W = (const float*)d_in[1];
    const float* U_b = (const float*)d_in[2];
    const float* V_W = (const float*)d_in[3];
    const float* V_b = (const float*)d_in[4];
    const float* H_W = (const float*)d_in[5];
    const float* H_b = (const float*)d_in[6];
    const float* Z_W = (const float*)d_in[7];
    const float* Z_b = (const float*)d_in[8];
    const float* F_W = (const float*)d_in[9];
    const float* F_b = (const float*)d_in[10];
    float* out = (float*)d_out;
    _Float16* ws16 = (_Float16*)d_ws;

    int N = in_sizes[0] / 2;          // 1048576; 128 points per block (2 waves x 64 pts)
    prep_weights<<<45, 64, 0, stream>>>(U_W, U_b, V_W, V_b, H_W, H_b, Z_W, Z_b, F_W, ws16);
    int blocks = N / 128;
    mlp_mfma<<<blocks, 128, 0, stream>>>(X, ws16, F_b, out);
}